// Round 1
// baseline (169.141 us; speedup 1.0000x reference)
//
#include <hip/hip_runtime.h>
#include <hip/hip_bf16.h>
#include <math.h>

// Shapes: B=8, T1=512, T2=128, LA=128, E=64, G=3E=192, DL=256
#define Bn 8
#define T1n 512
#define T2n 128
#define En 64
#define Gn 192
#define DLn 256

#define NEG_LOG2E  (-1.4426950408889634f)
#define TWO_LOG2E  (2.8853900817779268f)

typedef __attribute__((ext_vector_type(8))) short short8;
typedef __attribute__((ext_vector_type(4))) float float4v;

__device__ __forceinline__ float fast_rcp(float x) { return __builtin_amdgcn_rcpf(x); }

__device__ __forceinline__ float fast_exp2(float x) {
    float r;
    asm("v_exp_f32 %0, %1" : "=v"(r) : "v"(x));
    return r;
}

// round-to-nearest-even f32 -> bf16 bits
__device__ __forceinline__ unsigned short f32_to_bf16(float v) {
    unsigned u = __builtin_bit_cast(unsigned, v);
    u += 0x7FFFu + ((u >> 16) & 1u);
    return (unsigned short)(u >> 16);
}
__device__ __forceinline__ float bf16_to_f32(unsigned short s) {
    unsigned u = ((unsigned)s) << 16;
    return __builtin_bit_cast(float, u);
}

// async global->LDS, 16 B per lane (dest = wave-uniform base + lane*16)
__device__ __forceinline__ void load_lds16(const void* g, void* l) {
    __builtin_amdgcn_global_load_lds(
        (const __attribute__((address_space(1))) unsigned int*)g,
        (__attribute__((address_space(3))) unsigned int*)l, 16, 0, 0);
}

// ---------------------------------------------------------------------------
// K1: xg[d][b][t][j] = bf16( b_d[0][j] + emb(cs[b][t]) . K_d[:,j] ),
// with z/r gate columns (j<128) pre-scaled by -log2e so the scan's sigmoid
// is rcp(1+exp2(x)). grid: 1024 blocks x 384 threads (2 dirs x 192 gates).
// ---------------------------------------------------------------------------
__global__ __launch_bounds__(384) void k_pre(const int* __restrict__ char_seq,
                                             const float* __restrict__ emb_table,
                                             const float* __restrict__ Kf,
                                             const float* __restrict__ bf,
                                             const float* __restrict__ Kb,
                                             const float* __restrict__ bb,
                                             unsigned short* __restrict__ xgbf) {
    int bt = blockIdx.x;              // 0..1023
    int b = bt >> 7, t = bt & 127;
    int tid = threadIdx.x;            // 0..383
    __shared__ __align__(16) float emb[En];
    if (tid < En) {
        int cs = char_seq[b * T2n + t];
        emb[tid] = emb_table[cs * En + tid];
    }
    __syncthreads();
    int d = tid / Gn;                 // wave-uniform
    int j = tid - d * Gn;
    const float* K = d ? Kb : Kf;
    const float* bias = d ? bb : bf;  // row 0
    float acc = bias[j];
    #pragma unroll
    for (int e = 0; e < En; ++e) acc = fmaf(emb[e], K[e * Gn + j], acc);
    if (j < 128) acc *= NEG_LOG2E;    // pre-scale z,r gates
    xgbf[((size_t)(d * Bn + b) * T2n + t) * Gn + j] = f32_to_bf16(acc);
}

// ---------------------------------------------------------------------------
// K3: GRU scan. 16 blocks = (b, dir), ONE wave (64 threads). Best-measured
// structure (R8/R10): stage 48 KB bf16 xg -> LDS via global_load_lds (48
// issues, 1 wait); loop has zero global loads: h frags via 2x ds_read_b128,
// xg via 3 u16 LDS reads queued behind them, h.R via 12 chained MFMA pairs,
// gates via exp2/rcp (z/r pre-scaled by -log2e), mask from SGPR ballots,
// ctx store fire-and-forget, h round-trips through a 128 B LDS buffer.
// Measured plateau: ~930 cyc/step; bpermute / permlane / multi-wave
// alternatives all regressed (R9, R11).
// ---------------------------------------------------------------------------
__global__ __launch_bounds__(64) void k_scan(const unsigned short* __restrict__ xgbf,
                                             const float* __restrict__ Rf,
                                             const float* __restrict__ bf,
                                             const float* __restrict__ Rb,
                                             const float* __restrict__ bb,
                                             const int* __restrict__ char_seq,
                                             float* __restrict__ ctx) {
    int blk = blockIdx.x;             // 0..15
    int b = blk & 7, d = blk >> 3;
    int lane = threadIdx.x;           // 0..63
    int quad = lane >> 4, col = lane & 15;

    __shared__ __align__(16) unsigned short xg_l[T2n * Gn];   // 48 KB
    __shared__ __align__(16) unsigned short hb[En];           // 128 B

    // kick off the async xg staging first (48 x 1 KB, fire-and-forget)
    {
        const unsigned char* gb = (const unsigned char*)(xgbf + (size_t)(d * Bn + b) * T2n * Gn);
        unsigned char* lb = (unsigned char*)xg_l;
        #pragma unroll
        for (int i = 0; i < 48; ++i)
            load_lds16(gb + i * 1024 + lane * 16, lb + i * 1024 + lane * 16);
    }

    // overlap: ballots, R fragments, biases while staging is in flight
    unsigned long long mlo = __ballot(char_seq[b * T2n + lane] != 0);
    unsigned long long mhi = __ballot(char_seq[b * T2n + 64 + lane] != 0);

    const float* R = d ? Rb : Rf;
    const float* bias = d ? bb : bf;
    short8 frag[12][2];
    #pragma unroll
    for (int nt = 0; nt < 12; ++nt)
        #pragma unroll
        for (int kt = 0; kt < 2; ++kt) {
            short8 f;
            #pragma unroll
            for (int j = 0; j < 8; ++j) {
                float v = R[(kt * 32 + quad * 8 + j) * Gn + nt * 16 + col];
                if (nt < 8) v *= NEG_LOG2E;   // pre-scale z,r gate columns
                f[j] = (short)f32_to_bf16(v);
            }
            frag[nt][kt] = f;
        }
    float bz = bias[Gn + lane] * NEG_LOG2E;
    float br = bias[Gn + En + lane] * NEG_LOG2E;
    float bh = bias[Gn + 2 * En + lane];

    hb[lane] = 0;
    float hreg = 0.f, y = 0.f;
    float* ctxb = ctx + (size_t)b * T2n * 128 + d * En;
    int i0 = d ? (T2n - 1) : 0;
    int istep = d ? -1 : 1;
    bool q1 = (quad & 1) != 0, q2 = (quad & 2) != 0;
    const short8* ap = (const short8*)hb;

    // wait for staging to land before the loop reads xg_l
    asm volatile("s_waitcnt vmcnt(0)" ::: "memory");

    for (int step = 0; step < T2n; ++step) {
        int idx = i0 + istep * step;
        // h fragments first (the loop-carried LDS dependency)
        short8 a0 = ap[quad];
        short8 a1 = ap[4 + quad];
        // xg reads queue behind them (in-order DS); needed only after MFMAs
        int xb = idx * Gn + lane;
        unsigned short xzs = xg_l[xb];
        unsigned short xrs = xg_l[xb + 64];
        unsigned short xhs = xg_l[xb + 128];
        // 12 n-tiles, 2 chained k-tiles each (C=0 is a hoisted constant)
        float4v z4 = {0.f, 0.f, 0.f, 0.f};
        float4v acc[12];
        #pragma unroll
        for (int nt = 0; nt < 12; ++nt) {
            float4v p = __builtin_amdgcn_mfma_f32_16x16x32_bf16(a0, frag[nt][0], z4, 0, 0, 0);
            acc[nt] = __builtin_amdgcn_mfma_f32_16x16x32_bf16(a1, frag[nt][1], p, 0, 0, 0);
        }
        // select this lane's rz/rr/rh (gate col j = nt*16+col, nt = g*4+quad)
        float rz = (q2 ? (q1 ? acc[3].x : acc[2].x) : (q1 ? acc[1].x : acc[0].x)) + bz;
        float rr = (q2 ? (q1 ? acc[7].x : acc[6].x) : (q1 ? acc[5].x : acc[4].x)) + br;
        float rh = (q2 ? (q1 ? acc[11].x : acc[10].x) : (q1 ? acc[9].x : acc[8].x)) + bh;
        // gates: z/r args pre-scaled by -log2e -> sigmoid = rcp(1+exp2(.))
        float xz = bf16_to_f32(xzs), xr = bf16_to_f32(xrs), xh = bf16_to_f32(xhs);
        float z = fast_rcp(1.f + fast_exp2(xz + rz));
        float r = fast_rcp(1.f + fast_exp2(xr + rr));
        float a = fmaf(r, rh, xh);
        float hh = fmaf(-2.f, fast_rcp(1.f + fast_exp2(a * TWO_LOG2E)), 1.f);
        float hn = fmaf(z, hreg - hh, hh);
        bool m = (idx < 64) ? ((mlo >> idx) & 1ull) : ((mhi >> (idx - 64)) & 1ull);
        if (m) { hreg = hn; y = hn; }
        ctxb[idx * 128 + lane] = y;       // fire-and-forget global store
        hb[lane] = f32_to_bf16(hreg);     // same-wave LDS; lgkmcnt-ordered
    }
}

// ---------------------------------------------------------------------------
// K4: per (b,s): P0/P1 = ctx_row @ W1[tap], then
//   A = P0@W20, Cm = P1@W21, Bm = P1@W20 + P0@W21, sC = ctx_row . w_c,
//   plus 4 sL dot-products per block.
// ---------------------------------------------------------------------------
__global__ __launch_bounds__(128) void k_ctxw(const float* __restrict__ ctx,
                                              const float* __restrict__ conv1_w,
                                              const float* __restrict__ conv2_w,
                                              const float* __restrict__ w_char,
                                              const float* __restrict__ lstm,
                                              float* __restrict__ Am,
                                              float* __restrict__ Bm,
                                              float* __restrict__ Cm,
                                              float* __restrict__ sC,
                                              float* __restrict__ sL) {
    int bs = blockIdx.x;              // b*128+s
    int tid = threadIdx.x;            // 0..127
    {
        int wv = tid >> 6, lane = tid & 63;
        const float4* wl = (const float4*)w_char;
        #pragma unroll
        for (int q = 0; q < 2; ++q) {
            int bt = bs * 4 + wv * 2 + q;
            const float4* row = (const float4*)(lstm + (size_t)bt * DLn);
            float4 r4 = row[lane];
            float4 w4 = wl[lane];
            float s = r4.x * w4.x + r4.y * w4.y + r4.z * w4.z + r4.w * w4.w;
            #pragma unroll
            for (int off = 32; off; off >>= 1) s += __shfl_down(s, off);
            if (lane == 0) sL[bt] = s;
        }
    }
    __shared__ float crow[128];
    __shared__ float p0[En], p1[En];
    crow[tid] = ctx[(size_t)bs * 128 + tid];
    __syncthreads();
    if (tid < 64) {
        float s = crow[tid] * w_char[DLn + tid] + crow[64 + tid] * w_char[DLn + 64 + tid];
        #pragma unroll
        for (int off = 32; off; off >>= 1) s += __shfl_down(s, off);
        if (tid == 0) sC[bs] = s;
    }
    int tap = tid >> 6, o = tid & 63;
    const float* W = conv1_w + tap * 128 * En;
    float acc = 0.f;
    #pragma unroll
    for (int c = 0; c < 128; ++c) acc = fmaf(crow[c], W[c * En + o], acc);
    if (tap == 0) p0[o] = acc; else p1[o] = acc;
    __syncthreads();
    const float* W20 = conv2_w;            // [64][64]
    const float* W21 = conv2_w + En * En;
    if (tid < 64) {
        float a = 0.f, cm = 0.f;
        #pragma unroll
        for (int c = 0; c < En; ++c) {
            a  = fmaf(p0[c], W20[c * En + tid], a);
            cm = fmaf(p1[c], W21[c * En + tid], cm);
        }
        Am[(size_t)bs * En + tid] = a;
        Cm[(size_t)bs * En + tid] = cm;
    } else {
        int o2 = tid - 64;
        float bacc = 0.f;
        #pragma unroll
        for (int c = 0; c < En; ++c) {
            bacc = fmaf(p1[c], W20[c * En + o2], bacc);
            bacc = fmaf(p0[c], W21[c * En + o2], bacc);
        }
        Bm[(size_t)bs * En + o2] = bacc;
    }
}

// ---------------------------------------------------------------------------
// K5: per (b, 8-t tile): score rows -> char_weights; then
//   fe[b,t,o] = max_s ( sc[s]*A[s,o] + sc[s+1]*Bm[s+1,o] + sc[s+2]*Cm[s+2,o] + bb2[o] )
// ---------------------------------------------------------------------------
__global__ __launch_bounds__(128) void k_final(const float* __restrict__ sL,
                                               const float* __restrict__ sC,
                                               const float* __restrict__ w_char,
                                               const float* __restrict__ b_char,
                                               const float* __restrict__ conv1_b,
                                               const float* __restrict__ conv2_w,
                                               const float* __restrict__ conv2_b,
                                               const float* __restrict__ Am,
                                               const float* __restrict__ Bm,
                                               const float* __restrict__ Cm,
                                               float* __restrict__ fe,
                                               float* __restrict__ cw) {
    int blk = blockIdx.x;             // b(3b) x ttile(6b)
    int b = blk >> 6, ttile = blk & 63;
    int t0 = ttile * 8;
    int tid = threadIdx.x;            // 0..127
    float w_t = w_char[DLn + 128], w_i = w_char[DLn + 129], bc = b_char[0];
    __shared__ float sc8[8][T2n];
    {
        int s = tid;
        float sCs = sC[b * T2n + s] + w_i * (float)s + bc;
        #pragma unroll
        for (int tt = 0; tt < 8; ++tt) {
            int t = t0 + tt;
            float v = sL[b * T1n + t] + sCs + w_t * (float)t;
            sc8[tt][s] = v;
            cw[((size_t)(b * T1n + t)) * T2n + s] = v;
        }
    }
    int o = tid & 63, p = tid >> 6;
    float bb2 = conv2_b[o];
    #pragma unroll
    for (int c = 0; c < En; ++c)
        bb2 += conv1_b[c] * (conv2_w[c * En + o] + conv2_w[En * En + c * En + o]);
    __syncthreads();

    float acc[8];
    #pragma unroll
    for (int tt = 0; tt < 8; ++tt) acc[tt] = -__builtin_inff();
    const float* Ab = Am + (size_t)(b * T2n) * En + o;
    const float* Bb = Bm + (size_t)(b * T2n) * En + o;
    const float* Cb = Cm + (size_t)(b * T2n) * En + o;
    for (int s = p; s < T2n - 2; s += 2) {
        float a  = Ab[s * En];
        float bm = Bb[(s + 1) * En];
        float cm = Cb[(s + 2) * En];
        #pragma unroll
        for (int tt = 0; tt < 8; ++tt) {
            float v = fmaf(sc8[tt][s], a,
                      fmaf(sc8[tt][s + 1], bm,
                      fmaf(sc8[tt][s + 2], cm, bb2)));
            acc[tt] = fmaxf(acc[tt], v);
        }
    }
    __shared__ float red[64][9];
    if (p == 1) {
        #pragma unroll
        for (int tt = 0; tt < 8; ++tt) red[o][tt] = acc[tt];
    }
    __syncthreads();
    if (p == 0) {
        #pragma unroll
        for (int tt = 0; tt < 8; ++tt) {
            float v = fmaxf(acc[tt], red[o][tt]);
            fe[((size_t)(b * T1n + t0 + tt)) * En + o] = v;
        }
    }
}

// ---------------------------------------------------------------------------
extern "C" void kernel_launch(void* const* d_in, const int* in_sizes, int n_in,
                              void* d_out, int out_size, void* d_ws, size_t ws_size,
                              hipStream_t stream) {
    const float* lstm      = (const float*)d_in[0];
    const int*   char_seq  = (const int*)d_in[1];
    const float* emb_table = (const float*)d_in[2];
    const float* Kf        = (const float*)d_in[3];
    const float* Rf        = (const float*)d_in[4];
    const float* bf        = (const float*)d_in[5];
    const float* Kb        = (const float*)d_in[6];
    const float* Rb        = (const float*)d_in[7];
    const float* bb        = (const float*)d_in[8];
    const float* w_char    = (const float*)d_in[9];
    const float* b_char    = (const float*)d_in[10];
    const float* conv1_w   = (const float*)d_in[11];
    const float* conv1_b   = (const float*)d_in[12];
    const float* conv2_w   = (const float*)d_in[13];
    const float* conv2_b   = (const float*)d_in[14];

    float* out = (float*)d_out;
    float* fe = out;                             // 8*512*64 = 262144
    float* cw = out + Bn * T1n * En;             // 8*512*128 = 524288

    float* ws  = (float*)d_ws;
    unsigned short* xgbf = (unsigned short*)ws;  // 2*8*128*192 u16 = 393216 B
    float* ctx = ws + 98304;                     // 8*128*128 = 131072
    float* sC  = ctx + Bn * T2n * 128;           // 1024
    float* sL  = sC + Bn * T2n;                  // 4096
    float* Am  = sL + Bn * T1n;                  // 65536
    float* Bm  = Am + Bn * T2n * En;             // 65536
    float* Cm  = Bm + Bn * T2n * En;             // 65536

    k_pre <<<Bn * T2n, 384, 0, stream>>>(char_seq, emb_table, Kf, bf, Kb, bb, xgbf);
    k_scan<<<16, 64, 0, stream>>>(xgbf, Rf, bf, Rb, bb, char_seq, ctx);
    k_ctxw<<<Bn * T2n, 128, 0, stream>>>(ctx, conv1_w, conv2_w, w_char, lstm,
                                         Am, Bm, Cm, sC, sL);
    k_final<<<(Bn * T1n) / 8, 128, 0, stream>>>(sL, sC, w_char, b_char, conv1_b,
                                                conv2_w, conv2_b, Am, Bm, Cm, fe, cw);
}

// Round 2
// 169.134 us; speedup vs baseline: 1.0000x; 1.0000x over previous
//
#include <hip/hip_runtime.h>
#include <hip/hip_bf16.h>
#include <math.h>

// Shapes: B=8, T1=512, T2=128, LA=128, E=64, G=3E=192, DL=256
#define Bn 8
#define T1n 512
#define T2n 128
#define En 64
#define Gn 192
#define DLn 256

#define NEG_LOG2E  (-1.4426950408889634f)
#define TWO_LOG2E  (2.8853900817779268f)

typedef __attribute__((ext_vector_type(8))) short short8;
typedef __attribute__((ext_vector_type(4))) float float4v;

__device__ __forceinline__ float fast_rcp(float x) { return __builtin_amdgcn_rcpf(x); }

__device__ __forceinline__ float fast_exp2(float x) {
    float r;
    asm("v_exp_f32 %0, %1" : "=v"(r) : "v"(x));
    return r;
}

// round-to-nearest-even f32 -> bf16 bits
__device__ __forceinline__ unsigned short f32_to_bf16(float v) {
    unsigned u = __builtin_bit_cast(unsigned, v);
    u += 0x7FFFu + ((u >> 16) & 1u);
    return (unsigned short)(u >> 16);
}
__device__ __forceinline__ float bf16_to_f32(unsigned short s) {
    unsigned u = ((unsigned)s) << 16;
    return __builtin_bit_cast(float, u);
}

// async global->LDS, 16 B per lane (dest = wave-uniform base + lane*16)
__device__ __forceinline__ void load_lds16(const void* g, void* l) {
    __builtin_amdgcn_global_load_lds(
        (const __attribute__((address_space(1))) unsigned int*)g,
        (__attribute__((address_space(3))) unsigned int*)l, 16, 0, 0);
}

// ---------------------------------------------------------------------------
// K1: xg[d][b][t][j] = bf16( b_d[0][j] + emb(cs[b][t]) . K_d[:,j] ),
// with z/r gate columns (j<128) pre-scaled by -log2e so the scan's sigmoid
// is rcp(1+exp2(x)). grid: 1024 blocks x 384 threads (2 dirs x 192 gates).
// ---------------------------------------------------------------------------
__global__ __launch_bounds__(384) void k_pre(const int* __restrict__ char_seq,
                                             const float* __restrict__ emb_table,
                                             const float* __restrict__ Kf,
                                             const float* __restrict__ bf,
                                             const float* __restrict__ Kb,
                                             const float* __restrict__ bb,
                                             unsigned short* __restrict__ xgbf) {
    int bt = blockIdx.x;              // 0..1023
    int b = bt >> 7, t = bt & 127;
    int tid = threadIdx.x;            // 0..383
    __shared__ __align__(16) float emb[En];
    if (tid < En) {
        int cs = char_seq[b * T2n + t];
        emb[tid] = emb_table[cs * En + tid];
    }
    __syncthreads();
    int d = tid / Gn;                 // wave-uniform
    int j = tid - d * Gn;
    const float* K = d ? Kb : Kf;
    const float* bias = d ? bb : bf;  // row 0
    float acc = bias[j];
    #pragma unroll
    for (int e = 0; e < En; ++e) acc = fmaf(emb[e], K[e * Gn + j], acc);
    if (j < 128) acc *= NEG_LOG2E;    // pre-scale z,r gates
    xgbf[((size_t)(d * Bn + b) * T2n + t) * Gn + j] = f32_to_bf16(acc);
}

// ---------------------------------------------------------------------------
// K3: GRU scan. 16 blocks = (b, dir), ONE wave (64 threads).
// R1 change vs the 167 µs baseline: the 12 n-tiles' two k-half MFMAs were
// CHAINED through the C operand (p -> acc), which serializes each pair at
// full MFMA result latency (theory for the ~930 cyc/step plateau). Now the
// two k-halves accumulate into SEPARATE accumulators (24 fully independent
// MFMAs) and the .x halves are summed in the VALU tail. The recurrent bias
// rides in the C input of the first MFMA (loop-invariant), dropping 3
// dependent adds from the tail.
// ---------------------------------------------------------------------------
__global__ __launch_bounds__(64) void k_scan(const unsigned short* __restrict__ xgbf,
                                             const float* __restrict__ Rf,
                                             const float* __restrict__ bf,
                                             const float* __restrict__ Rb,
                                             const float* __restrict__ bb,
                                             const int* __restrict__ char_seq,
                                             float* __restrict__ ctx) {
    int blk = blockIdx.x;             // 0..15
    int b = blk & 7, d = blk >> 3;
    int lane = threadIdx.x;           // 0..63
    int quad = lane >> 4, col = lane & 15;

    __shared__ __align__(16) unsigned short xg_l[T2n * Gn];   // 48 KB
    __shared__ __align__(16) unsigned short hb[En];           // 128 B

    // kick off the async xg staging first (48 x 1 KB, fire-and-forget)
    {
        const unsigned char* gb = (const unsigned char*)(xgbf + (size_t)(d * Bn + b) * T2n * Gn);
        unsigned char* lb = (unsigned char*)xg_l;
        #pragma unroll
        for (int i = 0; i < 48; ++i)
            load_lds16(gb + i * 1024 + lane * 16, lb + i * 1024 + lane * 16);
    }

    // overlap: ballots, R fragments, biases while staging is in flight
    unsigned long long mlo = __ballot(char_seq[b * T2n + lane] != 0);
    unsigned long long mhi = __ballot(char_seq[b * T2n + 64 + lane] != 0);

    const float* R = d ? Rb : Rf;
    const float* bias = d ? bb : bf;
    short8 frag[12][2];
    #pragma unroll
    for (int nt = 0; nt < 12; ++nt)
        #pragma unroll
        for (int kt = 0; kt < 2; ++kt) {
            short8 f;
            #pragma unroll
            for (int j = 0; j < 8; ++j) {
                float v = R[(kt * 32 + quad * 8 + j) * Gn + nt * 16 + col];
                if (nt < 8) v *= NEG_LOG2E;   // pre-scale z,r gate columns
                f[j] = (short)f32_to_bf16(v);
            }
            frag[nt][kt] = f;
        }
    // recurrent bias (row 1) as loop-invariant C inputs: biasC[nt].x is the
    // bias of gate column j = nt*16 + col (pre-scaled for z/r tiles).
    float4v biasC[12];
    #pragma unroll
    for (int nt = 0; nt < 12; ++nt) {
        int j = nt * 16 + col;
        float bv = bias[Gn + j];
        if (nt < 8) bv *= NEG_LOG2E;
        float4v c = {bv, 0.f, 0.f, 0.f};
        biasC[nt] = c;
    }

    hb[lane] = 0;
    float hreg = 0.f, y = 0.f;
    float* ctxb = ctx + (size_t)b * T2n * 128 + d * En;
    int i0 = d ? (T2n - 1) : 0;
    int istep = d ? -1 : 1;
    bool q1 = (quad & 1) != 0, q2 = (quad & 2) != 0;
    const short8* ap = (const short8*)hb;

    // wait for staging to land before the loop reads xg_l
    asm volatile("s_waitcnt vmcnt(0)" ::: "memory");

    for (int step = 0; step < T2n; ++step) {
        int idx = i0 + istep * step;
        // h fragments first (the loop-carried LDS dependency)
        short8 a0 = ap[quad];
        short8 a1 = ap[4 + quad];
        // xg reads queue behind them (in-order DS); needed only after MFMAs
        int xb = idx * Gn + lane;
        unsigned short xzs = xg_l[xb];
        unsigned short xrs = xg_l[xb + 64];
        unsigned short xhs = xg_l[xb + 128];
        // 24 INDEPENDENT MFMAs: k-half 0 carries the bias in C, k-half 1
        // accumulates from zero; .x halves are summed afterwards.
        float4v z4 = {0.f, 0.f, 0.f, 0.f};
        float4v accA[12], accB[12];
        #pragma unroll
        for (int nt = 0; nt < 12; ++nt) {
            accA[nt] = __builtin_amdgcn_mfma_f32_16x16x32_bf16(a0, frag[nt][0], biasC[nt], 0, 0, 0);
            accB[nt] = __builtin_amdgcn_mfma_f32_16x16x32_bf16(a1, frag[nt][1], z4, 0, 0, 0);
        }
        float v[12];
        #pragma unroll
        for (int nt = 0; nt < 12; ++nt) v[nt] = accA[nt].x + accB[nt].x;
        // select this lane's rz/rr/rh (gate col j = nt*16+col, nt = g*4+quad)
        float rz = q2 ? (q1 ? v[3] : v[2]) : (q1 ? v[1] : v[0]);
        float rr = q2 ? (q1 ? v[7] : v[6]) : (q1 ? v[5] : v[4]);
        float rh = q2 ? (q1 ? v[11] : v[10]) : (q1 ? v[9] : v[8]);
        // gates: z/r args pre-scaled by -log2e -> sigmoid = rcp(1+exp2(.))
        float xz = bf16_to_f32(xzs), xr = bf16_to_f32(xrs), xh = bf16_to_f32(xhs);
        float z = fast_rcp(1.f + fast_exp2(xz + rz));
        float r = fast_rcp(1.f + fast_exp2(xr + rr));
        float a = fmaf(r, rh, xh);
        float hh = fmaf(-2.f, fast_rcp(1.f + fast_exp2(a * TWO_LOG2E)), 1.f);
        float hn = fmaf(z, hreg - hh, hh);
        bool m = (idx < 64) ? ((mlo >> idx) & 1ull) : ((mhi >> (idx - 64)) & 1ull);
        if (m) { hreg = hn; y = hn; }
        ctxb[idx * 128 + lane] = y;       // fire-and-forget global store
        hb[lane] = f32_to_bf16(hreg);     // same-wave LDS; lgkmcnt-ordered
    }
}

// ---------------------------------------------------------------------------
// K4: per (b,s): P0/P1 = ctx_row @ W1[tap], then
//   A = P0@W20, Cm = P1@W21, Bm = P1@W20 + P0@W21, sC = ctx_row . w_c,
//   plus 4 sL dot-products per block.
// ---------------------------------------------------------------------------
__global__ __launch_bounds__(128) void k_ctxw(const float* __restrict__ ctx,
                                              const float* __restrict__ conv1_w,
                                              const float* __restrict__ conv2_w,
                                              const float* __restrict__ w_char,
                                              const float* __restrict__ lstm,
                                              float* __restrict__ Am,
                                              float* __restrict__ Bm,
                                              float* __restrict__ Cm,
                                              float* __restrict__ sC,
                                              float* __restrict__ sL) {
    int bs = blockIdx.x;              // b*128+s
    int tid = threadIdx.x;            // 0..127
    {
        int wv = tid >> 6, lane = tid & 63;
        const float4* wl = (const float4*)w_char;
        #pragma unroll
        for (int q = 0; q < 2; ++q) {
            int bt = bs * 4 + wv * 2 + q;
            const float4* row = (const float4*)(lstm + (size_t)bt * DLn);
            float4 r4 = row[lane];
            float4 w4 = wl[lane];
            float s = r4.x * w4.x + r4.y * w4.y + r4.z * w4.z + r4.w * w4.w;
            #pragma unroll
            for (int off = 32; off; off >>= 1) s += __shfl_down(s, off);
            if (lane == 0) sL[bt] = s;
        }
    }
    __shared__ float crow[128];
    __shared__ float p0[En], p1[En];
    crow[tid] = ctx[(size_t)bs * 128 + tid];
    __syncthreads();
    if (tid < 64) {
        float s = crow[tid] * w_char[DLn + tid] + crow[64 + tid] * w_char[DLn + 64 + tid];
        #pragma unroll
        for (int off = 32; off; off >>= 1) s += __shfl_down(s, off);
        if (tid == 0) sC[bs] = s;
    }
    int tap = tid >> 6, o = tid & 63;
    const float* W = conv1_w + tap * 128 * En;
    float acc = 0.f;
    #pragma unroll
    for (int c = 0; c < 128; ++c) acc = fmaf(crow[c], W[c * En + o], acc);
    if (tap == 0) p0[o] = acc; else p1[o] = acc;
    __syncthreads();
    const float* W20 = conv2_w;            // [64][64]
    const float* W21 = conv2_w + En * En;
    if (tid < 64) {
        float a = 0.f, cm = 0.f;
        #pragma unroll
        for (int c = 0; c < En; ++c) {
            a  = fmaf(p0[c], W20[c * En + tid], a);
            cm = fmaf(p1[c], W21[c * En + tid], cm);
        }
        Am[(size_t)bs * En + tid] = a;
        Cm[(size_t)bs * En + tid] = cm;
    } else {
        int o2 = tid - 64;
        float bacc = 0.f;
        #pragma unroll
        for (int c = 0; c < En; ++c) {
            bacc = fmaf(p1[c], W20[c * En + o2], bacc);
            bacc = fmaf(p0[c], W21[c * En + o2], bacc);
        }
        Bm[(size_t)bs * En + o2] = bacc;
    }
}

// ---------------------------------------------------------------------------
// K5: per (b, 8-t tile): score rows -> char_weights; then
//   fe[b,t,o] = max_s ( sc[s]*A[s,o] + sc[s+1]*Bm[s+1,o] + sc[s+2]*Cm[s+2,o] + bb2[o] )
// ---------------------------------------------------------------------------
__global__ __launch_bounds__(128) void k_final(const float* __restrict__ sL,
                                               const float* __restrict__ sC,
                                               const float* __restrict__ w_char,
                                               const float* __restrict__ b_char,
                                               const float* __restrict__ conv1_b,
                                               const float* __restrict__ conv2_w,
                                               const float* __restrict__ conv2_b,
                                               const float* __restrict__ Am,
                                               const float* __restrict__ Bm,
                                               const float* __restrict__ Cm,
                                               float* __restrict__ fe,
                                               float* __restrict__ cw) {
    int blk = blockIdx.x;             // b(3b) x ttile(6b)
    int b = blk >> 6, ttile = blk & 63;
    int t0 = ttile * 8;
    int tid = threadIdx.x;            // 0..127
    float w_t = w_char[DLn + 128], w_i = w_char[DLn + 129], bc = b_char[0];
    __shared__ float sc8[8][T2n];
    {
        int s = tid;
        float sCs = sC[b * T2n + s] + w_i * (float)s + bc;
        #pragma unroll
        for (int tt = 0; tt < 8; ++tt) {
            int t = t0 + tt;
            float v = sL[b * T1n + t] + sCs + w_t * (float)t;
            sc8[tt][s] = v;
            cw[((size_t)(b * T1n + t)) * T2n + s] = v;
        }
    }
    int o = tid & 63, p = tid >> 6;
    float bb2 = conv2_b[o];
    #pragma unroll
    for (int c = 0; c < En; ++c)
        bb2 += conv1_b[c] * (conv2_w[c * En + o] + conv2_w[En * En + c * En + o]);
    __syncthreads();

    float acc[8];
    #pragma unroll
    for (int tt = 0; tt < 8; ++tt) acc[tt] = -__builtin_inff();
    const float* Ab = Am + (size_t)(b * T2n) * En + o;
    const float* Bb = Bm + (size_t)(b * T2n) * En + o;
    const float* Cb = Cm + (size_t)(b * T2n) * En + o;
    for (int s = p; s < T2n - 2; s += 2) {
        float a  = Ab[s * En];
        float bm = Bb[(s + 1) * En];
        float cm = Cb[(s + 2) * En];
        #pragma unroll
        for (int tt = 0; tt < 8; ++tt) {
            float v = fmaf(sc8[tt][s], a,
                      fmaf(sc8[tt][s + 1], bm,
                      fmaf(sc8[tt][s + 2], cm, bb2)));
            acc[tt] = fmaxf(acc[tt], v);
        }
    }
    __shared__ float red[64][9];
    if (p == 1) {
        #pragma unroll
        for (int tt = 0; tt < 8; ++tt) red[o][tt] = acc[tt];
    }
    __syncthreads();
    if (p == 0) {
        #pragma unroll
        for (int tt = 0; tt < 8; ++tt) {
            float v = fmaxf(acc[tt], red[o][tt]);
            fe[((size_t)(b * T1n + t0 + tt)) * En + o] = v;
        }
    }
}

// ---------------------------------------------------------------------------
extern "C" void kernel_launch(void* const* d_in, const int* in_sizes, int n_in,
                              void* d_out, int out_size, void* d_ws, size_t ws_size,
                              hipStream_t stream) {
    const float* lstm      = (const float*)d_in[0];
    const int*   char_seq  = (const int*)d_in[1];
    const float* emb_table = (const float*)d_in[2];
    const float* Kf        = (const float*)d_in[3];
    const float* Rf        = (const float*)d_in[4];
    const float* bf        = (const float*)d_in[5];
    const float* Kb        = (const float*)d_in[6];
    const float* Rb        = (const float*)d_in[7];
    const float* bb        = (const float*)d_in[8];
    const float* w_char    = (const float*)d_in[9];
    const float* b_char    = (const float*)d_in[10];
    const float* conv1_w   = (const float*)d_in[11];
    const float* conv1_b   = (const float*)d_in[12];
    const float* conv2_w   = (const float*)d_in[13];
    const float* conv2_b   = (const float*)d_in[14];

    float* out = (float*)d_out;
    float* fe = out;                             // 8*512*64 = 262144
    float* cw = out + Bn * T1n * En;             // 8*512*128 = 524288

    float* ws  = (float*)d_ws;
    unsigned short* xgbf = (unsigned short*)ws;  // 2*8*128*192 u16 = 393216 B
    float* ctx = ws + 98304;                     // 8*128*128 = 131072
    float* sC  = ctx + Bn * T2n * 128;           // 1024
    float* sL  = sC + Bn * T2n;                  // 4096
    float* Am  = sL + Bn * T1n;                  // 65536
    float* Bm  = Am + Bn * T2n * En;             // 65536
    float* Cm  = Bm + Bn * T2n * En;             // 65536

    k_pre <<<Bn * T2n, 384, 0, stream>>>(char_seq, emb_table, Kf, bf, Kb, bb, xgbf);
    k_scan<<<16, 64, 0, stream>>>(xgbf, Rf, bf, Rb, bb, char_seq, ctx);
    k_ctxw<<<Bn * T2n, 128, 0, stream>>>(ctx, conv1_w, conv2_w, w_char, lstm,
                                         Am, Bm, Cm, sC, sL);
    k_final<<<(Bn * T1n) / 8, 128, 0, stream>>>(sL, sC, w_char, b_char, conv1_b,
                                                conv2_w, conv2_b, Am, Bm, Cm, fe, cw);
}

// Round 3
// 150.335 us; speedup vs baseline: 1.1251x; 1.1250x over previous
//
#include <hip/hip_runtime.h>
#include <hip/hip_bf16.h>
#include <math.h>

// Shapes: B=8, T1=512, T2=128, LA=128, E=64, G=3E=192, DL=256
#define Bn 8
#define T1n 512
#define T2n 128
#define En 64
#define Gn 192
#define DLn 256

#define NEG_LOG2E  (-1.4426950408889634f)
#define TWO_LOG2E  (2.8853900817779268f)

typedef __attribute__((ext_vector_type(8))) short short8;
typedef __attribute__((ext_vector_type(4))) float float4v;

__device__ __forceinline__ float fast_rcp(float x) { return __builtin_amdgcn_rcpf(x); }

__device__ __forceinline__ float fast_exp2(float x) {
    float r;
    asm("v_exp_f32 %0, %1" : "=v"(r) : "v"(x));
    return r;
}

// round-to-nearest-even f32 -> bf16 bits
__device__ __forceinline__ unsigned short f32_to_bf16(float v) {
    unsigned u = __builtin_bit_cast(unsigned, v);
    u += 0x7FFFu + ((u >> 16) & 1u);
    return (unsigned short)(u >> 16);
}
__device__ __forceinline__ float bf16_to_f32(unsigned short s) {
    unsigned u = ((unsigned)s) << 16;
    return __builtin_bit_cast(float, u);
}

// async global->LDS, 16 B per lane (dest = wave-uniform base + lane*16)
__device__ __forceinline__ void load_lds16(const void* g, void* l) {
    __builtin_amdgcn_global_load_lds(
        (const __attribute__((address_space(1))) unsigned int*)g,
        (__attribute__((address_space(3))) unsigned int*)l, 16, 0, 0);
}

// ---------------------------------------------------------------------------
// K1: xg[d][b][t][j] = bf16( b_d[0][j] + emb(cs[b][t]) . K_d[:,j] ),
// with z/r gate columns (j<128) pre-scaled by -log2e so the scan's sigmoid
// is rcp(1+exp2(x)). grid: 1024 blocks x 384 threads (2 dirs x 192 gates).
// ---------------------------------------------------------------------------
__global__ __launch_bounds__(384) void k_pre(const int* __restrict__ char_seq,
                                             const float* __restrict__ emb_table,
                                             const float* __restrict__ Kf,
                                             const float* __restrict__ bf,
                                             const float* __restrict__ Kb,
                                             const float* __restrict__ bb,
                                             unsigned short* __restrict__ xgbf) {
    int bt = blockIdx.x;              // 0..1023
    int b = bt >> 7, t = bt & 127;
    int tid = threadIdx.x;            // 0..383
    __shared__ __align__(16) float emb[En];
    if (tid < En) {
        int cs = char_seq[b * T2n + t];
        emb[tid] = emb_table[cs * En + tid];
    }
    __syncthreads();
    int d = tid / Gn;                 // wave-uniform
    int j = tid - d * Gn;
    const float* K = d ? Kb : Kf;
    const float* bias = d ? bb : bf;  // row 0
    float acc = bias[j];
    #pragma unroll
    for (int e = 0; e < En; ++e) acc = fmaf(emb[e], K[e * Gn + j], acc);
    if (j < 128) acc *= NEG_LOG2E;    // pre-scale z,r gates
    xgbf[((size_t)(d * Bn + b) * T2n + t) * Gn + j] = f32_to_bf16(acc);
}

// ---------------------------------------------------------------------------
// K3: GRU scan. 16 blocks = (b, dir), FOUR waves (256 threads).
// R2 model fix: a single wave issues MFMAs at its SIMD's matrix-pipe rate
// (~16-19 cyc per 16x16x32 => 24 MFMAs ~ 460 cyc of the ~930 cyc step).
// So split the 24 MFMAs across 4 waves = 4 matrix pipes: wave w owns
// n-tiles {w, w+4, w+8} (complete z/r/h gates for units w*16..w*16+15),
// 6 MFMAs/wave/step. Broadcast A-rows mean every lane's .x is its tile
// value -> the quad-select cndmasks vanish. Cross-wave h exchange via a
// double-buffered 128 B LDS h vector + ONE raw s_barrier per step with
// lgkmcnt-only wait (NOT __syncthreads: its vmcnt(0) would drain the
// fire-and-forget ctx stores every step).
// ---------------------------------------------------------------------------
__global__ __launch_bounds__(256) void k_scan(const unsigned short* __restrict__ xgbf,
                                              const float* __restrict__ Rf,
                                              const float* __restrict__ bf,
                                              const float* __restrict__ Rb,
                                              const float* __restrict__ bb,
                                              const int* __restrict__ char_seq,
                                              float* __restrict__ ctx) {
    int blk = blockIdx.x;             // 0..15
    int b = blk & 7, d = blk >> 3;
    int tid = threadIdx.x;            // 0..255
    int w = tid >> 6;                 // wave 0..3
    int lane = tid & 63;
    int quad = lane >> 4, col = lane & 15;
    int u = w * 16 + col;             // this wave's unit slice

    __shared__ __align__(16) unsigned short xg_l[T2n * Gn];   // 48 KB
    __shared__ __align__(16) unsigned short h0[En];           // 128 B
    __shared__ __align__(16) unsigned short h1[En];           // 128 B

    // async xg staging, 48 x 1 KB split across the 4 waves
    {
        const unsigned char* gb = (const unsigned char*)(xgbf + (size_t)(d * Bn + b) * T2n * Gn);
        unsigned char* lb = (unsigned char*)xg_l;
        #pragma unroll
        for (int i = 0; i < 12; ++i) {
            int o = (w * 12 + i) * 1024 + lane * 16;
            load_lds16(gb + o, lb + o);
        }
    }

    // overlap: ballots, R fragments, biases while staging is in flight
    unsigned long long mlo = __ballot(char_seq[b * T2n + lane] != 0);
    unsigned long long mhi = __ballot(char_seq[b * T2n + 64 + lane] != 0);

    const float* R = d ? Rb : Rf;
    const float* bias = d ? bb : bf;
    // wave w's gate tiles: g=0 -> z (nt=w), g=1 -> r (nt=4+w), g=2 -> h (nt=8+w)
    short8 frag[3][2];
    float4v biasC[3];
    #pragma unroll
    for (int g = 0; g < 3; ++g) {
        int nt = g * 4 + w;
        #pragma unroll
        for (int kt = 0; kt < 2; ++kt) {
            short8 f;
            #pragma unroll
            for (int j = 0; j < 8; ++j) {
                float v = R[(kt * 32 + quad * 8 + j) * Gn + nt * 16 + col];
                if (g < 2) v *= NEG_LOG2E;   // pre-scale z,r gate columns
                f[j] = (short)f32_to_bf16(v);
            }
            frag[g][kt] = f;
        }
        float bv = bias[Gn + nt * 16 + col];
        if (g < 2) bv *= NEG_LOG2E;
        float4v c = {bv, 0.f, 0.f, 0.f};
        biasC[g] = c;
    }

    if (tid < En) h0[tid] = 0;
    float hreg = 0.f, y = 0.f;
    float* ctxb = ctx + (size_t)b * T2n * 128 + d * En;
    int i0 = d ? (T2n - 1) : 0;
    int istep = d ? -1 : 1;

    // staging + h0-init visible to all waves before the loop
    asm volatile("s_waitcnt vmcnt(0) lgkmcnt(0)" ::: "memory");
    __builtin_amdgcn_s_barrier();
    __builtin_amdgcn_sched_barrier(0);

    // one step: read h from CUR, write new h to NXT, one barrier
    #define SCAN_STEP(CUR, NXT, STEP)                                              \
    {                                                                              \
        int idx = i0 + istep * (STEP);                                             \
        const short8* ap = (const short8*)(CUR);                                   \
        short8 a0 = ap[quad];                                                      \
        short8 a1 = ap[4 + quad];                                                  \
        int xb = idx * Gn + u;                                                     \
        unsigned short xzs = xg_l[xb];                                             \
        unsigned short xrs = xg_l[xb + 64];                                        \
        unsigned short xhs = xg_l[xb + 128];                                       \
        float4v aZ = __builtin_amdgcn_mfma_f32_16x16x32_bf16(a0, frag[0][0], biasC[0], 0, 0, 0); \
        float4v aR = __builtin_amdgcn_mfma_f32_16x16x32_bf16(a0, frag[1][0], biasC[1], 0, 0, 0); \
        float4v aH = __builtin_amdgcn_mfma_f32_16x16x32_bf16(a0, frag[2][0], biasC[2], 0, 0, 0); \
        aZ = __builtin_amdgcn_mfma_f32_16x16x32_bf16(a1, frag[0][1], aZ, 0, 0, 0); \
        aR = __builtin_amdgcn_mfma_f32_16x16x32_bf16(a1, frag[1][1], aR, 0, 0, 0); \
        aH = __builtin_amdgcn_mfma_f32_16x16x32_bf16(a1, frag[2][1], aH, 0, 0, 0); \
        float xz = bf16_to_f32(xzs), xr = bf16_to_f32(xrs), xh = bf16_to_f32(xhs); \
        float z = fast_rcp(1.f + fast_exp2(xz + aZ.x));                            \
        float r = fast_rcp(1.f + fast_exp2(xr + aR.x));                            \
        float a = fmaf(r, aH.x, xh);                                               \
        float hh = fmaf(-2.f, fast_rcp(1.f + fast_exp2(a * TWO_LOG2E)), 1.f);      \
        float hn = fmaf(z, hreg - hh, hh);                                         \
        bool m = (idx < 64) ? ((mlo >> idx) & 1ull) : ((mhi >> (idx - 64)) & 1ull);\
        if (m) { hreg = hn; y = hn; }                                              \
        if (quad == 0) {                                                           \
            ctxb[idx * 128 + u] = y;                                               \
            (NXT)[u] = f32_to_bf16(hreg);                                          \
        }                                                                          \
        asm volatile("s_waitcnt lgkmcnt(0)" ::: "memory");                         \
        __builtin_amdgcn_sched_barrier(0);                                         \
        __builtin_amdgcn_s_barrier();                                              \
        __builtin_amdgcn_sched_barrier(0);                                         \
    }

    for (int sp = 0; sp < T2n / 2; ++sp) {
        SCAN_STEP(h0, h1, 2 * sp);
        SCAN_STEP(h1, h0, 2 * sp + 1);
    }
    #undef SCAN_STEP
}

// ---------------------------------------------------------------------------
// K4: per (b,s): P0/P1 = ctx_row @ W1[tap], then
//   A = P0@W20, Cm = P1@W21, Bm = P1@W20 + P0@W21, sC = ctx_row . w_c,
//   plus 4 sL dot-products per block.
// ---------------------------------------------------------------------------
__global__ __launch_bounds__(128) void k_ctxw(const float* __restrict__ ctx,
                                              const float* __restrict__ conv1_w,
                                              const float* __restrict__ conv2_w,
                                              const float* __restrict__ w_char,
                                              const float* __restrict__ lstm,
                                              float* __restrict__ Am,
                                              float* __restrict__ Bm,
                                              float* __restrict__ Cm,
                                              float* __restrict__ sC,
                                              float* __restrict__ sL) {
    int bs = blockIdx.x;              // b*128+s
    int tid = threadIdx.x;            // 0..127
    {
        int wv = tid >> 6, lane = tid & 63;
        const float4* wl = (const float4*)w_char;
        #pragma unroll
        for (int q = 0; q < 2; ++q) {
            int bt = bs * 4 + wv * 2 + q;
            const float4* row = (const float4*)(lstm + (size_t)bt * DLn);
            float4 r4 = row[lane];
            float4 w4 = wl[lane];
            float s = r4.x * w4.x + r4.y * w4.y + r4.z * w4.z + r4.w * w4.w;
            #pragma unroll
            for (int off = 32; off; off >>= 1) s += __shfl_down(s, off);
            if (lane == 0) sL[bt] = s;
        }
    }
    __shared__ float crow[128];
    __shared__ float p0[En], p1[En];
    crow[tid] = ctx[(size_t)bs * 128 + tid];
    __syncthreads();
    if (tid < 64) {
        float s = crow[tid] * w_char[DLn + tid] + crow[64 + tid] * w_char[DLn + 64 + tid];
        #pragma unroll
        for (int off = 32; off; off >>= 1) s += __shfl_down(s, off);
        if (tid == 0) sC[bs] = s;
    }
    int tap = tid >> 6, o = tid & 63;
    const float* W = conv1_w + tap * 128 * En;
    float acc = 0.f;
    #pragma unroll
    for (int c = 0; c < 128; ++c) acc = fmaf(crow[c], W[c * En + o], acc);
    if (tap == 0) p0[o] = acc; else p1[o] = acc;
    __syncthreads();
    const float* W20 = conv2_w;            // [64][64]
    const float* W21 = conv2_w + En * En;
    if (tid < 64) {
        float a = 0.f, cm = 0.f;
        #pragma unroll
        for (int c = 0; c < En; ++c) {
            a  = fmaf(p0[c], W20[c * En + tid], a);
            cm = fmaf(p1[c], W21[c * En + tid], cm);
        }
        Am[(size_t)bs * En + tid] = a;
        Cm[(size_t)bs * En + tid] = cm;
    } else {
        int o2 = tid - 64;
        float bacc = 0.f;
        #pragma unroll
        for (int c = 0; c < En; ++c) {
            bacc = fmaf(p1[c], W20[c * En + o2], bacc);
            bacc = fmaf(p0[c], W21[c * En + o2], bacc);
        }
        Bm[(size_t)bs * En + o2] = bacc;
    }
}

// ---------------------------------------------------------------------------
// K5: per (b, 8-t tile): score rows -> char_weights; then
//   fe[b,t,o] = max_s ( sc[s]*A[s,o] + sc[s+1]*Bm[s+1,o] + sc[s+2]*Cm[s+2,o] + bb2[o] )
// ---------------------------------------------------------------------------
__global__ __launch_bounds__(128) void k_final(const float* __restrict__ sL,
                                               const float* __restrict__ sC,
                                               const float* __restrict__ w_char,
                                               const float* __restrict__ b_char,
                                               const float* __restrict__ conv1_b,
                                               const float* __restrict__ conv2_w,
                                               const float* __restrict__ conv2_b,
                                               const float* __restrict__ Am,
                                               const float* __restrict__ Bm,
                                               const float* __restrict__ Cm,
                                               float* __restrict__ fe,
                                               float* __restrict__ cw) {
    int blk = blockIdx.x;             // b(3b) x ttile(6b)
    int b = blk >> 6, ttile = blk & 63;
    int t0 = ttile * 8;
    int tid = threadIdx.x;            // 0..127
    float w_t = w_char[DLn + 128], w_i = w_char[DLn + 129], bc = b_char[0];
    __shared__ float sc8[8][T2n];
    {
        int s = tid;
        float sCs = sC[b * T2n + s] + w_i * (float)s + bc;
        #pragma unroll
        for (int tt = 0; tt < 8; ++tt) {
            int t = t0 + tt;
            float v = sL[b * T1n + t] + sCs + w_t * (float)t;
            sc8[tt][s] = v;
            cw[((size_t)(b * T1n + t)) * T2n + s] = v;
        }
    }
    int o = tid & 63, p = tid >> 6;
    float bb2 = conv2_b[o];
    #pragma unroll
    for (int c = 0; c < En; ++c)
        bb2 += conv1_b[c] * (conv2_w[c * En + o] + conv2_w[En * En + c * En + o]);
    __syncthreads();

    float acc[8];
    #pragma unroll
    for (int tt = 0; tt < 8; ++tt) acc[tt] = -__builtin_inff();
    const float* Ab = Am + (size_t)(b * T2n) * En + o;
    const float* Bb = Bm + (size_t)(b * T2n) * En + o;
    const float* Cb = Cm + (size_t)(b * T2n) * En + o;
    for (int s = p; s < T2n - 2; s += 2) {
        float a  = Ab[s * En];
        float bm = Bb[(s + 1) * En];
        float cm = Cb[(s + 2) * En];
        #pragma unroll
        for (int tt = 0; tt < 8; ++tt) {
            float v = fmaf(sc8[tt][s], a,
                      fmaf(sc8[tt][s + 1], bm,
                      fmaf(sc8[tt][s + 2], cm, bb2)));
            acc[tt] = fmaxf(acc[tt], v);
        }
    }
    __shared__ float red[64][9];
    if (p == 1) {
        #pragma unroll
        for (int tt = 0; tt < 8; ++tt) red[o][tt] = acc[tt];
    }
    __syncthreads();
    if (p == 0) {
        #pragma unroll
        for (int tt = 0; tt < 8; ++tt) {
            float v = fmaxf(acc[tt], red[o][tt]);
            fe[((size_t)(b * T1n + t0 + tt)) * En + o] = v;
        }
    }
}

// ---------------------------------------------------------------------------
extern "C" void kernel_launch(void* const* d_in, const int* in_sizes, int n_in,
                              void* d_out, int out_size, void* d_ws, size_t ws_size,
                              hipStream_t stream) {
    const float* lstm      = (const float*)d_in[0];
    const int*   char_seq  = (const int*)d_in[1];
    const float* emb_table = (const float*)d_in[2];
    const float* Kf        = (const float*)d_in[3];
    const float* Rf        = (const float*)d_in[4];
    const float* bf        = (const float*)d_in[5];
    const float* Kb        = (const float*)d_in[6];
    const float* Rb        = (const float*)d_in[7];
    const float* bb        = (const float*)d_in[8];
    const float* w_char    = (const float*)d_in[9];
    const float* b_char    = (const float*)d_in[10];
    const float* conv1_w   = (const float*)d_in[11];
    const float* conv1_b   = (const float*)d_in[12];
    const float* conv2_w   = (const float*)d_in[13];
    const float* conv2_b   = (const float*)d_in[14];

    float* out = (float*)d_out;
    float* fe = out;                             // 8*512*64 = 262144
    float* cw = out + Bn * T1n * En;             // 8*512*128 = 524288

    float* ws  = (float*)d_ws;
    unsigned short* xgbf = (unsigned short*)ws;  // 2*8*128*192 u16 = 393216 B
    float* ctx = ws + 98304;                     // 8*128*128 = 131072
    float* sC  = ctx + Bn * T2n * 128;           // 1024
    float* sL  = sC + Bn * T2n;                  // 4096
    float* Am  = sL + Bn * T1n;                  // 65536
    float* Bm  = Am + Bn * T2n * En;             // 65536
    float* Cm  = Bm + Bn * T2n * En;             // 65536

    k_pre <<<Bn * T2n, 384, 0, stream>>>(char_seq, emb_table, Kf, bf, Kb, bb, xgbf);
    k_scan<<<16, 256, 0, stream>>>(xgbf, Rf, bf, Rb, bb, char_seq, ctx);
    k_ctxw<<<Bn * T2n, 128, 0, stream>>>(ctx, conv1_w, conv2_w, w_char, lstm,
                                         Am, Bm, Cm, sC, sL);
    k_final<<<(Bn * T1n) / 8, 128, 0, stream>>>(sL, sC, w_char, b_char, conv1_b,
                                                conv2_w, conv2_b, Am, Bm, Cm, fe, cw);
}

// Round 4
// 141.121 us; speedup vs baseline: 1.1985x; 1.0653x over previous
//
#include <hip/hip_runtime.h>
#include <hip/hip_bf16.h>
#include <math.h>

// Shapes: B=8, T1=512, T2=128, LA=128, E=64, G=3E=192, DL=256
#define Bn 8
#define T1n 512
#define T2n 128
#define En 64
#define Gn 192
#define DLn 256

#define NEG_LOG2E  (-1.4426950408889634f)
#define TWO_LOG2E  (2.8853900817779268f)

typedef __attribute__((ext_vector_type(8))) short short8;
typedef __attribute__((ext_vector_type(4))) float float4v;

__device__ __forceinline__ float fast_rcp(float x) { return __builtin_amdgcn_rcpf(x); }

__device__ __forceinline__ float fast_exp2(float x) {
    float r;
    asm("v_exp_f32 %0, %1" : "=v"(r) : "v"(x));
    return r;
}

// round-to-nearest-even f32 -> bf16 bits
__device__ __forceinline__ unsigned short f32_to_bf16(float v) {
    unsigned u = __builtin_bit_cast(unsigned, v);
    u += 0x7FFFu + ((u >> 16) & 1u);
    return (unsigned short)(u >> 16);
}
__device__ __forceinline__ float bf16_to_f32(unsigned short s) {
    unsigned u = ((unsigned)s) << 16;
    return __builtin_bit_cast(float, u);
}

// async global->LDS, 16 B per lane (dest = wave-uniform base + lane*16)
__device__ __forceinline__ void load_lds16(const void* g, void* l) {
    __builtin_amdgcn_global_load_lds(
        (const __attribute__((address_space(1))) unsigned int*)g,
        (__attribute__((address_space(3))) unsigned int*)l, 16, 0, 0);
}

// ---------------------------------------------------------------------------
// K1: xg[d][b][t][j] = bf16( b_d[0][j] + emb(cs[b][t]) . K_d[:,j] ),
// with z/r gate columns (j<128) pre-scaled by -log2e so the scan's sigmoid
// is rcp(1+exp2(x)). grid: 1024 blocks x 384 threads (2 dirs x 192 gates).
// ---------------------------------------------------------------------------
__global__ __launch_bounds__(384) void k_pre(const int* __restrict__ char_seq,
                                             const float* __restrict__ emb_table,
                                             const float* __restrict__ Kf,
                                             const float* __restrict__ bf,
                                             const float* __restrict__ Kb,
                                             const float* __restrict__ bb,
                                             unsigned short* __restrict__ xgbf) {
    int bt = blockIdx.x;              // 0..1023
    int b = bt >> 7, t = bt & 127;
    int tid = threadIdx.x;            // 0..383
    __shared__ __align__(16) float emb[En];
    if (tid < En) {
        int cs = char_seq[b * T2n + t];
        emb[tid] = emb_table[cs * En + tid];
    }
    __syncthreads();
    int d = tid / Gn;                 // wave-uniform
    int j = tid - d * Gn;
    const float* K = d ? Kb : Kf;
    const float* bias = d ? bb : bf;  // row 0
    float acc = bias[j];
    #pragma unroll
    for (int e = 0; e < En; ++e) acc = fmaf(emb[e], K[e * Gn + j], acc);
    if (j < 128) acc *= NEG_LOG2E;    // pre-scale z,r gates
    xgbf[((size_t)(d * Bn + b) * T2n + t) * Gn + j] = f32_to_bf16(acc);
}

// ---------------------------------------------------------------------------
// K3: GRU scan. 16 blocks = (b, dir), FOUR waves (256 threads).
// 4-wave MFMA split (R3, verified −19 µs): wave w owns n-tiles {w, w+4, w+8}
// = complete z/r/h gates for units w*16..w*16+15, 6 MFMAs/wave/step.
// Cross-wave h exchange via double-buffered 128 B LDS h vector + ONE raw
// s_barrier per step with lgkmcnt-only wait (NOT __syncthreads: its vmcnt(0)
// would drain the fire-and-forget ctx stores every step).
// R4 micro: h LDS write issued BEFORE the ctx global store so the barrier's
// lgkm wait starts as early as possible.
// ---------------------------------------------------------------------------
__global__ __launch_bounds__(256) void k_scan(const unsigned short* __restrict__ xgbf,
                                              const float* __restrict__ Rf,
                                              const float* __restrict__ bf,
                                              const float* __restrict__ Rb,
                                              const float* __restrict__ bb,
                                              const int* __restrict__ char_seq,
                                              float* __restrict__ ctx) {
    int blk = blockIdx.x;             // 0..15
    int b = blk & 7, d = blk >> 3;
    int tid = threadIdx.x;            // 0..255
    int w = tid >> 6;                 // wave 0..3
    int lane = tid & 63;
    int quad = lane >> 4, col = lane & 15;
    int u = w * 16 + col;             // this wave's unit slice

    __shared__ __align__(16) unsigned short xg_l[T2n * Gn];   // 48 KB
    __shared__ __align__(16) unsigned short h0[En];           // 128 B
    __shared__ __align__(16) unsigned short h1[En];           // 128 B

    // async xg staging, 48 x 1 KB split across the 4 waves
    {
        const unsigned char* gb = (const unsigned char*)(xgbf + (size_t)(d * Bn + b) * T2n * Gn);
        unsigned char* lb = (unsigned char*)xg_l;
        #pragma unroll
        for (int i = 0; i < 12; ++i) {
            int o = (w * 12 + i) * 1024 + lane * 16;
            load_lds16(gb + o, lb + o);
        }
    }

    // overlap: ballots, R fragments, biases while staging is in flight
    unsigned long long mlo = __ballot(char_seq[b * T2n + lane] != 0);
    unsigned long long mhi = __ballot(char_seq[b * T2n + 64 + lane] != 0);

    const float* R = d ? Rb : Rf;
    const float* bias = d ? bb : bf;
    // wave w's gate tiles: g=0 -> z (nt=w), g=1 -> r (nt=4+w), g=2 -> h (nt=8+w)
    short8 frag[3][2];
    float4v biasC[3];
    #pragma unroll
    for (int g = 0; g < 3; ++g) {
        int nt = g * 4 + w;
        #pragma unroll
        for (int kt = 0; kt < 2; ++kt) {
            short8 f;
            #pragma unroll
            for (int j = 0; j < 8; ++j) {
                float v = R[(kt * 32 + quad * 8 + j) * Gn + nt * 16 + col];
                if (g < 2) v *= NEG_LOG2E;   // pre-scale z,r gate columns
                f[j] = (short)f32_to_bf16(v);
            }
            frag[g][kt] = f;
        }
        float bv = bias[Gn + nt * 16 + col];
        if (g < 2) bv *= NEG_LOG2E;
        float4v c = {bv, 0.f, 0.f, 0.f};
        biasC[g] = c;
    }

    if (tid < En) h0[tid] = 0;
    float hreg = 0.f, y = 0.f;
    float* ctxb = ctx + (size_t)b * T2n * 128 + d * En;
    int i0 = d ? (T2n - 1) : 0;
    int istep = d ? -1 : 1;

    // staging + h0-init visible to all waves before the loop
    asm volatile("s_waitcnt vmcnt(0) lgkmcnt(0)" ::: "memory");
    __builtin_amdgcn_s_barrier();
    __builtin_amdgcn_sched_barrier(0);

    // one step: read h from CUR, write new h to NXT, one barrier
    #define SCAN_STEP(CUR, NXT, STEP)                                              \
    {                                                                              \
        int idx = i0 + istep * (STEP);                                             \
        const short8* ap = (const short8*)(CUR);                                   \
        short8 a0 = ap[quad];                                                      \
        short8 a1 = ap[4 + quad];                                                  \
        int xb = idx * Gn + u;                                                     \
        unsigned short xzs = xg_l[xb];                                             \
        unsigned short xrs = xg_l[xb + 64];                                        \
        unsigned short xhs = xg_l[xb + 128];                                       \
        float4v aZ = __builtin_amdgcn_mfma_f32_16x16x32_bf16(a0, frag[0][0], biasC[0], 0, 0, 0); \
        float4v aR = __builtin_amdgcn_mfma_f32_16x16x32_bf16(a0, frag[1][0], biasC[1], 0, 0, 0); \
        float4v aH = __builtin_amdgcn_mfma_f32_16x16x32_bf16(a0, frag[2][0], biasC[2], 0, 0, 0); \
        aZ = __builtin_amdgcn_mfma_f32_16x16x32_bf16(a1, frag[0][1], aZ, 0, 0, 0); \
        aR = __builtin_amdgcn_mfma_f32_16x16x32_bf16(a1, frag[1][1], aR, 0, 0, 0); \
        aH = __builtin_amdgcn_mfma_f32_16x16x32_bf16(a1, frag[2][1], aH, 0, 0, 0); \
        float xz = bf16_to_f32(xzs), xr = bf16_to_f32(xrs), xh = bf16_to_f32(xhs); \
        float z = fast_rcp(1.f + fast_exp2(xz + aZ.x));                            \
        float r = fast_rcp(1.f + fast_exp2(xr + aR.x));                            \
        float a = fmaf(r, aH.x, xh);                                               \
        float hh = fmaf(-2.f, fast_rcp(1.f + fast_exp2(a * TWO_LOG2E)), 1.f);      \
        float hn = fmaf(z, hreg - hh, hh);                                         \
        bool m = (idx < 64) ? ((mlo >> idx) & 1ull) : ((mhi >> (idx - 64)) & 1ull);\
        if (m) { hreg = hn; y = hn; }                                              \
        if (quad == 0) {                                                           \
            (NXT)[u] = f32_to_bf16(hreg);                                          \
            ctxb[idx * 128 + u] = y;                                               \
        }                                                                          \
        asm volatile("s_waitcnt lgkmcnt(0)" ::: "memory");                         \
        __builtin_amdgcn_sched_barrier(0);                                         \
        __builtin_amdgcn_s_barrier();                                              \
        __builtin_amdgcn_sched_barrier(0);                                         \
    }

    for (int sp = 0; sp < T2n / 2; ++sp) {
        SCAN_STEP(h0, h1, 2 * sp);
        SCAN_STEP(h1, h0, 2 * sp + 1);
    }
    #undef SCAN_STEP
}

// ---------------------------------------------------------------------------
// K4: per (b,s): P0/P1 = ctx_row @ W1[tap], then
//   A = P0@W20, Cm = P1@W21, Bm = P1@W20 + P0@W21, sC = ctx_row . w_c,
//   plus 4 sL dot-products per block.
// ---------------------------------------------------------------------------
__global__ __launch_bounds__(128) void k_ctxw(const float* __restrict__ ctx,
                                              const float* __restrict__ conv1_w,
                                              const float* __restrict__ conv2_w,
                                              const float* __restrict__ w_char,
                                              const float* __restrict__ lstm,
                                              float* __restrict__ Am,
                                              float* __restrict__ Bm,
                                              float* __restrict__ Cm,
                                              float* __restrict__ sC,
                                              float* __restrict__ sL) {
    int bs = blockIdx.x;              // b*128+s
    int tid = threadIdx.x;            // 0..127
    {
        int wv = tid >> 6, lane = tid & 63;
        const float4* wl = (const float4*)w_char;
        #pragma unroll
        for (int q = 0; q < 2; ++q) {
            int bt = bs * 4 + wv * 2 + q;
            const float4* row = (const float4*)(lstm + (size_t)bt * DLn);
            float4 r4 = row[lane];
            float4 w4 = wl[lane];
            float s = r4.x * w4.x + r4.y * w4.y + r4.z * w4.z + r4.w * w4.w;
            #pragma unroll
            for (int off = 32; off; off >>= 1) s += __shfl_down(s, off);
            if (lane == 0) sL[bt] = s;
        }
    }
    __shared__ float crow[128];
    __shared__ float p0[En], p1[En];
    crow[tid] = ctx[(size_t)bs * 128 + tid];
    __syncthreads();
    if (tid < 64) {
        float s = crow[tid] * w_char[DLn + tid] + crow[64 + tid] * w_char[DLn + 64 + tid];
        #pragma unroll
        for (int off = 32; off; off >>= 1) s += __shfl_down(s, off);
        if (tid == 0) sC[bs] = s;
    }
    int tap = tid >> 6, o = tid & 63;
    const float* W = conv1_w + tap * 128 * En;
    float acc = 0.f;
    #pragma unroll
    for (int c = 0; c < 128; ++c) acc = fmaf(crow[c], W[c * En + o], acc);
    if (tap == 0) p0[o] = acc; else p1[o] = acc;
    __syncthreads();
    const float* W20 = conv2_w;            // [64][64]
    const float* W21 = conv2_w + En * En;
    if (tid < 64) {
        float a = 0.f, cm = 0.f;
        #pragma unroll
        for (int c = 0; c < En; ++c) {
            a  = fmaf(p0[c], W20[c * En + tid], a);
            cm = fmaf(p1[c], W21[c * En + tid], cm);
        }
        Am[(size_t)bs * En + tid] = a;
        Cm[(size_t)bs * En + tid] = cm;
    } else {
        int o2 = tid - 64;
        float bacc = 0.f;
        #pragma unroll
        for (int c = 0; c < En; ++c) {
            bacc = fmaf(p1[c], W20[c * En + o2], bacc);
            bacc = fmaf(p0[c], W21[c * En + o2], bacc);
        }
        Bm[(size_t)bs * En + o2] = bacc;
    }
}

// ---------------------------------------------------------------------------
// K5: per (b, 8-t tile): score rows -> char_weights; then
//   fe[b,t,o] = max_s ( sc[s]*A[s,o] + sc[s+1]*Bm[s+1,o] + sc[s+2]*Cm[s+2,o] + bb2[o] )
// R4: 256 threads, 4-way s-partition (p = tid>>6, stride 4). Same value set
// into the fmax reduction -> bit-identical output; halves the per-thread
// serial loop and doubles waves/SIMD to hide the Am/Bm/Cm load latency.
// ---------------------------------------------------------------------------
__global__ __launch_bounds__(256) void k_final(const float* __restrict__ sL,
                                               const float* __restrict__ sC,
                                               const float* __restrict__ w_char,
                                               const float* __restrict__ b_char,
                                               const float* __restrict__ conv1_b,
                                               const float* __restrict__ conv2_w,
                                               const float* __restrict__ conv2_b,
                                               const float* __restrict__ Am,
                                               const float* __restrict__ Bm,
                                               const float* __restrict__ Cm,
                                               float* __restrict__ fe,
                                               float* __restrict__ cw) {
    int blk = blockIdx.x;             // b(3b) x ttile(6b)
    int b = blk >> 6, ttile = blk & 63;
    int t0 = ttile * 8;
    int tid = threadIdx.x;            // 0..255
    float w_t = w_char[DLn + 128], w_i = w_char[DLn + 129], bc = b_char[0];
    __shared__ float sc8[8][T2n];
    if (tid < T2n) {
        int s = tid;
        float sCs = sC[b * T2n + s] + w_i * (float)s + bc;
        #pragma unroll
        for (int tt = 0; tt < 8; ++tt) {
            int t = t0 + tt;
            float v = sL[b * T1n + t] + sCs + w_t * (float)t;
            sc8[tt][s] = v;
            cw[((size_t)(b * T1n + t)) * T2n + s] = v;
        }
    }
    int o = tid & 63, p = tid >> 6;   // p = 0..3
    float bb2 = conv2_b[o];
    #pragma unroll
    for (int c = 0; c < En; ++c)
        bb2 += conv1_b[c] * (conv2_w[c * En + o] + conv2_w[En * En + c * En + o]);
    __syncthreads();

    float acc[8];
    #pragma unroll
    for (int tt = 0; tt < 8; ++tt) acc[tt] = -__builtin_inff();
    const float* Ab = Am + (size_t)(b * T2n) * En + o;
    const float* Bb = Bm + (size_t)(b * T2n) * En + o;
    const float* Cb = Cm + (size_t)(b * T2n) * En + o;
    for (int s = p; s < T2n - 2; s += 4) {
        float a  = Ab[s * En];
        float bm = Bb[(s + 1) * En];
        float cm = Cb[(s + 2) * En];
        #pragma unroll
        for (int tt = 0; tt < 8; ++tt) {
            float v = fmaf(sc8[tt][s], a,
                      fmaf(sc8[tt][s + 1], bm,
                      fmaf(sc8[tt][s + 2], cm, bb2)));
            acc[tt] = fmaxf(acc[tt], v);
        }
    }
    __shared__ float red[3][64][9];   // +1 pad breaks the stride-8 bank walk
    if (p) {
        #pragma unroll
        for (int tt = 0; tt < 8; ++tt) red[p - 1][o][tt] = acc[tt];
    }
    __syncthreads();
    if (p == 0) {
        #pragma unroll
        for (int tt = 0; tt < 8; ++tt) {
            float v = fmaxf(fmaxf(acc[tt], red[0][o][tt]),
                            fmaxf(red[1][o][tt], red[2][o][tt]));
            fe[((size_t)(b * T1n + t0 + tt)) * En + o] = v;
        }
    }
}

// ---------------------------------------------------------------------------
extern "C" void kernel_launch(void* const* d_in, const int* in_sizes, int n_in,
                              void* d_out, int out_size, void* d_ws, size_t ws_size,
                              hipStream_t stream) {
    const float* lstm      = (const float*)d_in[0];
    const int*   char_seq  = (const int*)d_in[1];
    const float* emb_table = (const float*)d_in[2];
    const float* Kf        = (const float*)d_in[3];
    const float* Rf        = (const float*)d_in[4];
    const float* bf        = (const float*)d_in[5];
    const float* Kb        = (const float*)d_in[6];
    const float* Rb        = (const float*)d_in[7];
    const float* bb        = (const float*)d_in[8];
    const float* w_char    = (const float*)d_in[9];
    const float* b_char    = (const float*)d_in[10];
    const float* conv1_w   = (const float*)d_in[11];
    const float* conv1_b   = (const float*)d_in[12];
    const float* conv2_w   = (const float*)d_in[13];
    const float* conv2_b   = (const float*)d_in[14];

    float* out = (float*)d_out;
    float* fe = out;                             // 8*512*64 = 262144
    float* cw = out + Bn * T1n * En;             // 8*512*128 = 524288

    float* ws  = (float*)d_ws;
    unsigned short* xgbf = (unsigned short*)ws;  // 2*8*128*192 u16 = 393216 B
    float* ctx = ws + 98304;                     // 8*128*128 = 131072
    float* sC  = ctx + Bn * T2n * 128;           // 1024
    float* sL  = sC + Bn * T2n;                  // 4096
    float* Am  = sL + Bn * T1n;                  // 65536
    float* Bm  = Am + Bn * T2n * En;             // 65536
    float* Cm  = Bm + Bn * T2n * En;             // 65536

    k_pre <<<Bn * T2n, 384, 0, stream>>>(char_seq, emb_table, Kf, bf, Kb, bb, xgbf);
    k_scan<<<16, 256, 0, stream>>>(xgbf, Rf, bf, Rb, bb, char_seq, ctx);
    k_ctxw<<<Bn * T2n, 128, 0, stream>>>(ctx, conv1_w, conv2_w, w_char, lstm,
                                         Am, Bm, Cm, sC, sL);
    k_final<<<(Bn * T1n) / 8, 256, 0, stream>>>(sL, sC, w_char, b_char, conv1_b,
                                                conv2_w, conv2_b, Am, Bm, Cm, fe, cw);
}

// Round 5
// 136.359 us; speedup vs baseline: 1.2404x; 1.0349x over previous
//
#include <hip/hip_runtime.h>
#include <hip/hip_bf16.h>
#include <math.h>

// Shapes: B=8, T1=512, T2=128, LA=128, E=64, G=3E=192, DL=256
#define Bn 8
#define T1n 512
#define T2n 128
#define En 64
#define Gn 192
#define DLn 256

#define NEG_LOG2E  (-1.4426950408889634f)
#define TWO_LOG2E  (2.8853900817779268f)

typedef __attribute__((ext_vector_type(8))) short short8;
typedef __attribute__((ext_vector_type(4))) float float4v;

__device__ __forceinline__ float fast_rcp(float x) { return __builtin_amdgcn_rcpf(x); }

__device__ __forceinline__ float fast_exp2(float x) {
    float r;
    asm("v_exp_f32 %0, %1" : "=v"(r) : "v"(x));
    return r;
}

// round-to-nearest-even f32 -> bf16 bits
__device__ __forceinline__ unsigned short f32_to_bf16(float v) {
    unsigned u = __builtin_bit_cast(unsigned, v);
    u += 0x7FFFu + ((u >> 16) & 1u);
    return (unsigned short)(u >> 16);
}
__device__ __forceinline__ float bf16_to_f32(unsigned short s) {
    unsigned u = ((unsigned)s) << 16;
    return __builtin_bit_cast(float, u);
}

// async global->LDS, 16 B per lane (dest = wave-uniform base + lane*16)
__device__ __forceinline__ void load_lds16(const void* g, void* l) {
    __builtin_amdgcn_global_load_lds(
        (const __attribute__((address_space(1))) unsigned int*)g,
        (__attribute__((address_space(3))) unsigned int*)l, 16, 0, 0);
}

// ---------------------------------------------------------------------------
// K1: xg[d][b][t][j] = bf16( b_d[0][j] + emb(cs[b][t]) . K_d[:,j] ),
// with z/r gate columns (j<128) pre-scaled by -log2e so the scan's sigmoid
// is rcp(1+exp2(x)). grid: 1024 blocks x 384 threads (2 dirs x 192 gates).
// R5: also computes sL[bt] (lstm . w_l dot-products) with waves 0-3
// (relocated from k_ctxw; identical code/indexing -> bit-identical).
// ---------------------------------------------------------------------------
__global__ __launch_bounds__(384) void k_pre(const int* __restrict__ char_seq,
                                             const float* __restrict__ emb_table,
                                             const float* __restrict__ Kf,
                                             const float* __restrict__ bf,
                                             const float* __restrict__ Kb,
                                             const float* __restrict__ bb,
                                             const float* __restrict__ lstm,
                                             const float* __restrict__ w_char,
                                             unsigned short* __restrict__ xgbf,
                                             float* __restrict__ sL) {
    int bt = blockIdx.x;              // 0..1023  (= b*128 + t2)
    int b = bt >> 7, t = bt & 127;
    int tid = threadIdx.x;            // 0..383
    __shared__ __align__(16) float emb[En];
    if (tid < En) {
        int cs = char_seq[b * T2n + t];
        emb[tid] = emb_table[cs * En + tid];
    }
    // sL: waves 0-3 each compute one lstm-row dot (bt4 = blockIdx*4+wv
    // spans b*512 + t1 for all (b,t1)); independent of the emb/xg path.
    {
        int wv = tid >> 6, lane = tid & 63;
        if (wv < 4) {
            int bt4 = bt * 4 + wv;
            const float4* row = (const float4*)(lstm + (size_t)bt4 * DLn);
            const float4* wl = (const float4*)w_char;
            float4 r4 = row[lane];
            float4 w4 = wl[lane];
            float s = r4.x * w4.x + r4.y * w4.y + r4.z * w4.z + r4.w * w4.w;
            #pragma unroll
            for (int off = 32; off; off >>= 1) s += __shfl_down(s, off);
            if (lane == 0) sL[bt4] = s;
        }
    }
    __syncthreads();
    int d = tid / Gn;                 // wave-uniform
    int j = tid - d * Gn;
    const float* K = d ? Kb : Kf;
    const float* bias = d ? bb : bf;  // row 0
    float acc = bias[j];
    #pragma unroll
    for (int e = 0; e < En; ++e) acc = fmaf(emb[e], K[e * Gn + j], acc);
    if (j < 128) acc *= NEG_LOG2E;    // pre-scale z,r gates
    xgbf[((size_t)(d * Bn + b) * T2n + t) * Gn + j] = f32_to_bf16(acc);
}

// ---------------------------------------------------------------------------
// K3: GRU scan. 16 blocks = (b, dir), FOUR waves (256 threads).
// 4-wave MFMA split (R3, verified −19 µs): wave w owns n-tiles {w, w+4, w+8}
// = complete z/r/h gates for units w*16..w*16+15, 6 MFMAs/wave/step.
// Cross-wave h exchange via double-buffered 128 B LDS h vector + ONE raw
// s_barrier per step with lgkmcnt-only wait (NOT __syncthreads: its vmcnt(0)
// would drain the fire-and-forget ctx stores every step).
// R5: xg reads software-pipelined one step ahead into registers — the 3
// LDS reads issue during step t's MFMA/tail shadow and are consumed in
// step t+1, removing them from the post-barrier critical region.
// NOTE (R2/R4 model): chained-MFMA C-dependency costs ~0 here — with the
// 3-gate interleave the 2nd k-half issues after >= result latency (m119:
// chain-2 reaches peak). Do NOT re-split the pairs (R1 regressed).
// ---------------------------------------------------------------------------
__global__ __launch_bounds__(256) void k_scan(const unsigned short* __restrict__ xgbf,
                                              const float* __restrict__ Rf,
                                              const float* __restrict__ bf,
                                              const float* __restrict__ Rb,
                                              const float* __restrict__ bb,
                                              const int* __restrict__ char_seq,
                                              float* __restrict__ ctx) {
    int blk = blockIdx.x;             // 0..15
    int b = blk & 7, d = blk >> 3;
    int tid = threadIdx.x;            // 0..255
    int w = tid >> 6;                 // wave 0..3
    int lane = tid & 63;
    int quad = lane >> 4, col = lane & 15;
    int u = w * 16 + col;             // this wave's unit slice

    __shared__ __align__(16) unsigned short xg_l[T2n * Gn];   // 48 KB
    __shared__ __align__(16) unsigned short h0[En];           // 128 B
    __shared__ __align__(16) unsigned short h1[En];           // 128 B

    // async xg staging, 48 x 1 KB split across the 4 waves
    {
        const unsigned char* gb = (const unsigned char*)(xgbf + (size_t)(d * Bn + b) * T2n * Gn);
        unsigned char* lb = (unsigned char*)xg_l;
        #pragma unroll
        for (int i = 0; i < 12; ++i) {
            int o = (w * 12 + i) * 1024 + lane * 16;
            load_lds16(gb + o, lb + o);
        }
    }

    // overlap: ballots, R fragments, biases while staging is in flight
    unsigned long long mlo = __ballot(char_seq[b * T2n + lane] != 0);
    unsigned long long mhi = __ballot(char_seq[b * T2n + 64 + lane] != 0);

    const float* R = d ? Rb : Rf;
    const float* bias = d ? bb : bf;
    // wave w's gate tiles: g=0 -> z (nt=w), g=1 -> r (nt=4+w), g=2 -> h (nt=8+w)
    short8 frag[3][2];
    float4v biasC[3];
    #pragma unroll
    for (int g = 0; g < 3; ++g) {
        int nt = g * 4 + w;
        #pragma unroll
        for (int kt = 0; kt < 2; ++kt) {
            short8 f;
            #pragma unroll
            for (int j = 0; j < 8; ++j) {
                float v = R[(kt * 32 + quad * 8 + j) * Gn + nt * 16 + col];
                if (g < 2) v *= NEG_LOG2E;   // pre-scale z,r gate columns
                f[j] = (short)f32_to_bf16(v);
            }
            frag[g][kt] = f;
        }
        float bv = bias[Gn + nt * 16 + col];
        if (g < 2) bv *= NEG_LOG2E;
        float4v c = {bv, 0.f, 0.f, 0.f};
        biasC[g] = c;
    }

    if (tid < En) h0[tid] = 0;
    float hreg = 0.f, y = 0.f;
    float* ctxb = ctx + (size_t)b * T2n * 128 + d * En;
    int i0 = d ? (T2n - 1) : 0;
    int istep = d ? -1 : 1;

    // staging + h0-init visible to all waves before the loop
    asm volatile("s_waitcnt vmcnt(0) lgkmcnt(0)" ::: "memory");
    __builtin_amdgcn_s_barrier();
    __builtin_amdgcn_sched_barrier(0);

    // prologue: step-0 xg already in registers
    unsigned short xz_a = xg_l[i0 * Gn + u];
    unsigned short xr_a = xg_l[i0 * Gn + u + 64];
    unsigned short xh_a = xg_l[i0 * Gn + u + 128];
    unsigned short xz_b, xr_b, xh_b;

    // one step: read h from CUR, write new h to NXT, one barrier.
    // consumes xg regs XC_*, prefetches step+1 xg into XN_*.
    #define SCAN_STEP(CUR, NXT, STEP, XCz, XCr, XCh, XNz, XNr, XNh)                \
    {                                                                              \
        int idx = i0 + istep * (STEP);                                             \
        const short8* ap = (const short8*)(CUR);                                   \
        short8 a0 = ap[quad];                                                      \
        short8 a1 = ap[4 + quad];                                                  \
        int idxn = idx + istep;                                                    \
        if ((unsigned)idxn >= T2n) idxn = idx;                                     \
        int xbn = idxn * Gn + u;                                                   \
        XNz = xg_l[xbn];                                                           \
        XNr = xg_l[xbn + 64];                                                      \
        XNh = xg_l[xbn + 128];                                                     \
        float4v aZ = __builtin_amdgcn_mfma_f32_16x16x32_bf16(a0, frag[0][0], biasC[0], 0, 0, 0); \
        float4v aR = __builtin_amdgcn_mfma_f32_16x16x32_bf16(a0, frag[1][0], biasC[1], 0, 0, 0); \
        float4v aH = __builtin_amdgcn_mfma_f32_16x16x32_bf16(a0, frag[2][0], biasC[2], 0, 0, 0); \
        aZ = __builtin_amdgcn_mfma_f32_16x16x32_bf16(a1, frag[0][1], aZ, 0, 0, 0); \
        aR = __builtin_amdgcn_mfma_f32_16x16x32_bf16(a1, frag[1][1], aR, 0, 0, 0); \
        aH = __builtin_amdgcn_mfma_f32_16x16x32_bf16(a1, frag[2][1], aH, 0, 0, 0); \
        float xz = bf16_to_f32(XCz), xr = bf16_to_f32(XCr), xh = bf16_to_f32(XCh); \
        float z = fast_rcp(1.f + fast_exp2(xz + aZ.x));                            \
        float r = fast_rcp(1.f + fast_exp2(xr + aR.x));                            \
        float a = fmaf(r, aH.x, xh);                                               \
        float hh = fmaf(-2.f, fast_rcp(1.f + fast_exp2(a * TWO_LOG2E)), 1.f);      \
        float hn = fmaf(z, hreg - hh, hh);                                         \
        bool m = (idx < 64) ? ((mlo >> idx) & 1ull) : ((mhi >> (idx - 64)) & 1ull);\
        if (m) { hreg = hn; y = hn; }                                              \
        if (quad == 0) {                                                           \
            (NXT)[u] = f32_to_bf16(hreg);                                          \
            ctxb[idx * 128 + u] = y;                                               \
        }                                                                          \
        asm volatile("s_waitcnt lgkmcnt(0)" ::: "memory");                         \
        __builtin_amdgcn_sched_barrier(0);                                         \
        __builtin_amdgcn_s_barrier();                                              \
        __builtin_amdgcn_sched_barrier(0);                                         \
    }

    for (int sp = 0; sp < T2n / 2; ++sp) {
        SCAN_STEP(h0, h1, 2 * sp,     xz_a, xr_a, xh_a, xz_b, xr_b, xh_b);
        SCAN_STEP(h1, h0, 2 * sp + 1, xz_b, xr_b, xh_b, xz_a, xr_a, xh_a);
    }
    #undef SCAN_STEP
}

// ---------------------------------------------------------------------------
// K4: per (b,s): P0/P1 = ctx_row @ W1[tap], then
//   A = P0@W20, Cm = P1@W21, Bm = P1@W20 + P0@W21, sC = ctx_row . w_c.
// (sL dots moved to k_pre in R5.)
// ---------------------------------------------------------------------------
__global__ __launch_bounds__(128) void k_ctxw(const float* __restrict__ ctx,
                                              const float* __restrict__ conv1_w,
                                              const float* __restrict__ conv2_w,
                                              const float* __restrict__ w_char,
                                              float* __restrict__ Am,
                                              float* __restrict__ Bm,
                                              float* __restrict__ Cm,
                                              float* __restrict__ sC) {
    int bs = blockIdx.x;              // b*128+s
    int tid = threadIdx.x;            // 0..127
    __shared__ float crow[128];
    __shared__ float p0[En], p1[En];
    crow[tid] = ctx[(size_t)bs * 128 + tid];
    __syncthreads();
    if (tid < 64) {
        float s = crow[tid] * w_char[DLn + tid] + crow[64 + tid] * w_char[DLn + 64 + tid];
        #pragma unroll
        for (int off = 32; off; off >>= 1) s += __shfl_down(s, off);
        if (tid == 0) sC[bs] = s;
    }
    int tap = tid >> 6, o = tid & 63;
    const float* W = conv1_w + tap * 128 * En;
    float acc = 0.f;
    #pragma unroll
    for (int c = 0; c < 128; ++c) acc = fmaf(crow[c], W[c * En + o], acc);
    if (tap == 0) p0[o] = acc; else p1[o] = acc;
    __syncthreads();
    const float* W20 = conv2_w;            // [64][64]
    const float* W21 = conv2_w + En * En;
    if (tid < 64) {
        float a = 0.f, cm = 0.f;
        #pragma unroll
        for (int c = 0; c < En; ++c) {
            a  = fmaf(p0[c], W20[c * En + tid], a);
            cm = fmaf(p1[c], W21[c * En + tid], cm);
        }
        Am[(size_t)bs * En + tid] = a;
        Cm[(size_t)bs * En + tid] = cm;
    } else {
        int o2 = tid - 64;
        float bacc = 0.f;
        #pragma unroll
        for (int c = 0; c < En; ++c) {
            bacc = fmaf(p1[c], W20[c * En + o2], bacc);
            bacc = fmaf(p0[c], W21[c * En + o2], bacc);
        }
        Bm[(size_t)bs * En + o2] = bacc;
    }
}

// ---------------------------------------------------------------------------
// K5: per (b, 8-t tile): score rows -> char_weights; then
//   fe[b,t,o] = max_s ( sc[s]*A[s,o] + sc[s+1]*Bm[s+1,o] + sc[s+2]*Cm[s+2,o] + bb2[o] )
// R5: 512 threads, 8-way s-partition (p = tid>>6, stride 8); fmax over the
// identical value set -> bit-identical. ~16 iters/thread, 32 waves/CU.
// ---------------------------------------------------------------------------
__global__ __launch_bounds__(512) void k_final(const float* __restrict__ sL,
                                               const float* __restrict__ sC,
                                               const float* __restrict__ w_char,
                                               const float* __restrict__ b_char,
                                               const float* __restrict__ conv1_b,
                                               const float* __restrict__ conv2_w,
                                               const float* __restrict__ conv2_b,
                                               const float* __restrict__ Am,
                                               const float* __restrict__ Bm,
                                               const float* __restrict__ Cm,
                                               float* __restrict__ fe,
                                               float* __restrict__ cw) {
    int blk = blockIdx.x;             // b(3b) x ttile(6b)
    int b = blk >> 6, ttile = blk & 63;
    int t0 = ttile * 8;
    int tid = threadIdx.x;            // 0..511
    float w_t = w_char[DLn + 128], w_i = w_char[DLn + 129], bc = b_char[0];
    __shared__ float sc8[8][T2n];
    if (tid < T2n) {
        int s = tid;
        float sCs = sC[b * T2n + s] + w_i * (float)s + bc;
        #pragma unroll
        for (int tt = 0; tt < 8; ++tt) {
            int t = t0 + tt;
            float v = sL[b * T1n + t] + sCs + w_t * (float)t;
            sc8[tt][s] = v;
            cw[((size_t)(b * T1n + t)) * T2n + s] = v;
        }
    }
    int o = tid & 63, p = tid >> 6;   // p = 0..7
    float bb2 = conv2_b[o];
    #pragma unroll
    for (int c = 0; c < En; ++c)
        bb2 += conv1_b[c] * (conv2_w[c * En + o] + conv2_w[En * En + c * En + o]);
    __syncthreads();

    float acc[8];
    #pragma unroll
    for (int tt = 0; tt < 8; ++tt) acc[tt] = -__builtin_inff();
    const float* Ab = Am + (size_t)(b * T2n) * En + o;
    const float* Bb = Bm + (size_t)(b * T2n) * En + o;
    const float* Cb = Cm + (size_t)(b * T2n) * En + o;
    #pragma unroll 4
    for (int s = p; s < T2n - 2; s += 8) {
        float a  = Ab[s * En];
        float bm = Bb[(s + 1) * En];
        float cm = Cb[(s + 2) * En];
        #pragma unroll
        for (int tt = 0; tt < 8; ++tt) {
            float v = fmaf(sc8[tt][s], a,
                      fmaf(sc8[tt][s + 1], bm,
                      fmaf(sc8[tt][s + 2], cm, bb2)));
            acc[tt] = fmaxf(acc[tt], v);
        }
    }
    __shared__ float red[7][64][9];   // +1 pad breaks the stride-8 bank walk
    if (p) {
        #pragma unroll
        for (int tt = 0; tt < 8; ++tt) red[p - 1][o][tt] = acc[tt];
    }
    __syncthreads();
    if (p == 0) {
        #pragma unroll
        for (int tt = 0; tt < 8; ++tt) {
            float v = acc[tt];
            #pragma unroll
            for (int q = 0; q < 7; ++q) v = fmaxf(v, red[q][o][tt]);
            fe[((size_t)(b * T1n + t0 + tt)) * En + o] = v;
        }
    }
}

// ---------------------------------------------------------------------------
extern "C" void kernel_launch(void* const* d_in, const int* in_sizes, int n_in,
                              void* d_out, int out_size, void* d_ws, size_t ws_size,
                              hipStream_t stream) {
    const float* lstm      = (const float*)d_in[0];
    const int*   char_seq  = (const int*)d_in[1];
    const float* emb_table = (const float*)d_in[2];
    const float* Kf        = (const float*)d_in[3];
    const float* Rf        = (const float*)d_in[4];
    const float* bf        = (const float*)d_in[5];
    const float* Kb        = (const float*)d_in[6];
    const float* Rb        = (const float*)d_in[7];
    const float* bb        = (const float*)d_in[8];
    const float* w_char    = (const float*)d_in[9];
    const float* b_char    = (const float*)d_in[10];
    const float* conv1_w   = (const float*)d_in[11];
    const float* conv1_b   = (const float*)d_in[12];
    const float* conv2_w   = (const float*)d_in[13];
    const float* conv2_b   = (const float*)d_in[14];

    float* out = (float*)d_out;
    float* fe = out;                             // 8*512*64 = 262144
    float* cw = out + Bn * T1n * En;             // 8*512*128 = 524288

    float* ws  = (float*)d_ws;
    unsigned short* xgbf = (unsigned short*)ws;  // 2*8*128*192 u16 = 393216 B
    float* ctx = ws + 98304;                     // 8*128*128 = 131072
    float* sC  = ctx + Bn * T2n * 128;           // 1024
    float* sL  = sC + Bn * T2n;                  // 4096
    float* Am  = sL + Bn * T1n;                  // 65536
    float* Bm  = Am + Bn * T2n * En;             // 65536
    float* Cm  = Bm + Bn * T2n * En;             // 65536

    k_pre <<<Bn * T2n, 384, 0, stream>>>(char_seq, emb_table, Kf, bf, Kb, bb,
                                         lstm, w_char, xgbf, sL);
    k_scan<<<16, 256, 0, stream>>>(xgbf, Rf, bf, Rb, bb, char_seq, ctx);
    k_ctxw<<<Bn * T2n, 128, 0, stream>>>(ctx, conv1_w, conv2_w, w_char,
                                         Am, Bm, Cm, sC);
    k_final<<<(Bn * T1n) / 8, 512, 0, stream>>>(sL, sC, w_char, b_char, conv1_b,
                                                conv2_w, conv2_b, Am, Bm, Cm, fe, cw);
}